// Round 1
// baseline (1013.558 us; speedup 1.0000x reference)
//
#include <hip/hip_runtime.h>

#define S_SP   13824        // 24*24*24 spatial
#define CHAN   256
#define NQ     27648        // 2 * 13824
#define KCODES 2048
#define CS     3538944      // CHAN * S_SP
#define OFF_Q   1
#define OFF_PPL 7077889
#define OFF_ENC 7077890LL
#define OFF_IDX 63700994LL

// ---------------- K1: per-code squared norms ----------------
__global__ __launch_bounds__(256) void wnorm_k(const float* __restrict__ W,
                                               float* __restrict__ wn) {
  int t = threadIdx.x;
  int k = blockIdx.x * 4 + (t >> 6);
  int l = t & 63;
  const float* Wp = W + (size_t)k * CHAN;
  float s = 0.f;
#pragma unroll
  for (int j = 0; j < 4; ++j) {
    float v = Wp[l + 64 * j];
    s = fmaf(v, v, s);
  }
  for (int off = 32; off; off >>= 1) s += __shfl_down(s, off);
  if (l == 0) wn[k] = s;
}

// ---------------- K2: distance + argmin (fp32) ----------------
// 64 queries per block staged in LDS d-major [256][64]; 8 waves x 8 codes/thread.
// Score = wnorm[k] - 2*dot (||x||^2 constant per query, irrelevant for argmin).
// Writes idx as float; near-ties (gap < 0.02) flagged via negative sentinel.
__global__ __launch_bounds__(512) void dist_argmin(const float* __restrict__ X,
                                                   const float* __restrict__ W,
                                                   const float* __restrict__ wn,
                                                   float* __restrict__ idx_out) {
  __shared__ float xs[CHAN * 64];   // 64 KB, reused for reduction afterwards
  int t = threadIdx.x;
  int qbase = blockIdx.x * 64;
  int b = qbase / S_SP;
  int s0 = qbase % S_SP;
  const float* xb = X + (size_t)b * CS + s0;

  int q = t & 63;
  int d0 = t >> 6;                  // 0..7
  for (int r = 0; r < 32; ++r) {
    int d = d0 + (r << 3);
    xs[d * 64 + q] = xb[(size_t)d * S_SP + q];
  }
  __syncthreads();

  int wave = t >> 6;
  float b1 = 3.4e38f, b2 = 3.4e38f;
  int i1 = 0;

  for (int it = 0; it < 32; ++it) {
    int kb = (it << 6) + (wave << 3);
    kb = __builtin_amdgcn_readfirstlane(kb);
    const float* Wp = W + (size_t)kb * CHAN;
    float acc[8];
#pragma unroll
    for (int c = 0; c < 8; ++c) acc[c] = 0.f;

#pragma unroll 4
    for (int d = 0; d < CHAN; d += 2) {
      float x0 = xs[d * 64 + q];
      float x1 = xs[(d + 1) * 64 + q];
#pragma unroll
      for (int c = 0; c < 8; ++c) {
        float w0 = Wp[c * CHAN + d];
        float w1 = Wp[c * CHAN + d + 1];
        acc[c] = fmaf(x1, w1, fmaf(x0, w0, acc[c]));
      }
    }
#pragma unroll
    for (int c = 0; c < 8; ++c) {
      int k = kb + c;
      float sc = wn[k] - 2.0f * acc[c];
      if (sc < b1) { b2 = b1; b1 = sc; i1 = k; }
      else if (sc < b2) { b2 = sc; }
    }
  }

  // cross-wave reduction: reuse xs as [wave][q][3]
  __syncthreads();
  xs[(wave * 64 + q) * 3 + 0] = b1;
  xs[(wave * 64 + q) * 3 + 1] = __int_as_float(i1);
  xs[(wave * 64 + q) * 3 + 2] = b2;
  __syncthreads();

  if (t < 64) {
    float B1 = xs[t * 3 + 0];
    int   I1 = __float_as_int(xs[t * 3 + 1]);
    float B2 = xs[t * 3 + 2];
    for (int w2 = 1; w2 < 8; ++w2) {
      float c1 = xs[(w2 * 64 + t) * 3 + 0];
      int   ci = __float_as_int(xs[(w2 * 64 + t) * 3 + 1]);
      float c2 = xs[(w2 * 64 + t) * 3 + 2];
      if (c1 < B1 || (c1 == B1 && ci < I1)) {
        B2 = fminf(B1, c2);
        B1 = c1; I1 = ci;
      } else {
        B2 = fminf(B2, c1);
      }
    }
    int n = qbase + t;
    bool flag = (B2 - B1) < 0.02f;
    idx_out[n] = flag ? -(float)(I1 + 1) : (float)I1;
  }
}

// ---------------- K3: fp64 exact refine of flagged queries ----------------
__global__ __launch_bounds__(256) void refine(const float* __restrict__ X,
                                              const float* __restrict__ W,
                                              float* __restrict__ idx_out) {
  int n = blockIdx.x;
  if (idx_out[n] >= 0.f) return;   // uniform per block
  int t = threadIdx.x;
  int b = n / S_SP, s = n % S_SP;

  __shared__ double xd[CHAN];
  xd[t] = (double)X[(size_t)b * CS + (size_t)t * S_SP + s];
  __syncthreads();

  double best = 1e300;
  int bi = 1 << 30;
  for (int j = 0; j < 8; ++j) {
    int k = t * 8 + j;
    const float* Wp = W + (size_t)k * CHAN;
    double dsum = 0.0;
    for (int d = 0; d < CHAN; ++d) {
      double df = xd[d] - (double)Wp[d];
      dsum = fma(df, df, dsum);
    }
    if (dsum < best) { best = dsum; bi = k; }
  }

  __shared__ double rv[256];
  __shared__ int    ri[256];
  rv[t] = best; ri[t] = bi;
  __syncthreads();
  for (int off = 128; off > 0; off >>= 1) {
    if (t < off) {
      if (rv[t + off] < rv[t] || (rv[t + off] == rv[t] && ri[t + off] < ri[t])) {
        rv[t] = rv[t + off]; ri[t] = ri[t + off];
      }
    }
    __syncthreads();
  }
  if (t == 0) idx_out[n] = (float)ri[0];
}

// ---------------- K5: gather quantized, one-hot, histogram, loss partials ----------------
__global__ __launch_bounds__(256) void scatter_stats(const float* __restrict__ X,
                                                     const float* __restrict__ W,
                                                     float* __restrict__ outF,
                                                     int* __restrict__ counts,
                                                     float* __restrict__ loss_acc) {
  __shared__ int h[KCODES];
  __shared__ float wred[4];
  int t = threadIdx.x;
  for (int j = t; j < KCODES; j += 256) h[j] = 0;
  __syncthreads();

  int n = blockIdx.x * 256 + t;
  int idx = (int)outF[OFF_IDX + n];
  atomicAdd(&h[idx], 1);
  outF[OFF_ENC + (size_t)n * KCODES + idx] = 1.0f;

  int b = n / S_SP, s = n % S_SP;
  const float* Wp = W + (size_t)idx * CHAN;
  const float* xp = X + (size_t)b * CS + s;
  float* qp = outF + OFF_Q + (size_t)b * CS + s;

  float lsum = 0.f;
#pragma unroll 4
  for (int c = 0; c < CHAN; ++c) {
    float wv = Wp[c];
    float xv = xp[(size_t)c * S_SP];
    qp[(size_t)c * S_SP] = wv;
    float df = wv - xv;
    lsum = fmaf(df, df, lsum);
  }

  for (int off = 32; off; off >>= 1) lsum += __shfl_down(lsum, off);
  if ((t & 63) == 0) wred[t >> 6] = lsum;
  __syncthreads();
  if (t == 0) atomicAdd(loss_acc, wred[0] + wred[1] + wred[2] + wred[3]);

  for (int j = t; j < KCODES; j += 256) {
    int v = h[j];
    if (v) atomicAdd(&counts[j], v);
  }
}

// ---------------- K6: finalize loss + perplexity ----------------
__global__ __launch_bounds__(256) void finalize(const int* __restrict__ counts,
                                                const float* __restrict__ loss_acc,
                                                float* __restrict__ outF) {
  __shared__ double red[256];
  int t = threadIdx.x;
  double H = 0.0;
  for (int k = t; k < KCODES; k += 256) {
    double p = (double)counts[k] / (double)NQ;
    H += p * log(p + 1e-10);
  }
  red[t] = H;
  __syncthreads();
  for (int off = 128; off > 0; off >>= 1) {
    if (t < off) red[t] += red[t + off];
    __syncthreads();
  }
  if (t == 0) {
    outF[0] = 0.25f * (loss_acc[0] / 7077888.0f);
    outF[OFF_PPL] = (float)exp(-red[0]);
  }
}

extern "C" void kernel_launch(void* const* d_in, const int* in_sizes, int n_in,
                              void* d_out, int out_size, void* d_ws, size_t ws_size,
                              hipStream_t stream) {
  const float* X = (const float*)d_in[0];
  const float* W = (const float*)d_in[1];
  float* outF = (float*)d_out;
  char* ws = (char*)d_ws;
  float* wn = (float*)ws;                       // 2048 f32
  int*   counts = (int*)(ws + 8192);            // 2048 i32
  float* loss_acc = (float*)(ws + 16384);       // 1 f32

  hipMemsetAsync(ws + 8192, 0, 8192 + 16, stream);
  hipMemsetAsync((char*)d_out + OFF_ENC * 4, 0, (size_t)NQ * KCODES * 4, stream);

  wnorm_k<<<KCODES / 4, 256, 0, stream>>>(W, wn);
  dist_argmin<<<NQ / 64, 512, 0, stream>>>(X, W, wn, outF + OFF_IDX);
  refine<<<NQ, 256, 0, stream>>>(X, W, outF + OFF_IDX);
  scatter_stats<<<NQ / 256, 256, 0, stream>>>(X, W, outF, counts, loss_acc);
  finalize<<<1, 256, 0, stream>>>(counts, loss_acc, outF);
}